// Round 8
// baseline (592.119 us; speedup 1.0000x reference)
//
#include <hip/hip_runtime.h>
#include <hip/hip_bf16.h>

#define BB 8
#define CC 256
#define HH 128
#define WW 128
#define KS 9
#define NPIX (BB*HH*WW)   // 131072
#define KDIM (4*CC)       // 1024

typedef __attribute__((ext_vector_type(8))) short bf16x8;
typedef __attribute__((ext_vector_type(4))) float f32x4;

static __device__ __forceinline__ unsigned short f2bf(float f) {
  union { float f; unsigned u; } v; v.f = f;
  unsigned r = v.u + 0x7FFF + ((v.u >> 16) & 1);   // RNE
  return (unsigned short)(r >> 16);
}
static __device__ __forceinline__ float bf2f(unsigned short u) {
  union { unsigned u; float f; } v; v.u = ((unsigned)u) << 16;
  return v.f;
}

// global -> LDS direct copy, 16B per lane
static __device__ __forceinline__ void gload_lds16(const void* g, void* l) {
  __builtin_amdgcn_global_load_lds(
      (const __attribute__((address_space(1))) void*)g,
      (__attribute__((address_space(3))) void*)l, 16, 0, 0);
}

// ---------------------------------------------------------------------------
// Prep A': A'[o][k'] bf16, k' = c*4 + t, from wproj[o][t*256 + c] (fp32)
// ---------------------------------------------------------------------------
__global__ void prep_kernel(const float* __restrict__ wproj,
                            unsigned short* __restrict__ Ap) {
  int idx = blockIdx.x * 256 + threadIdx.x;    // 0 .. 262143
  int o  = idx >> 10;
  int kp = idx & 1023;
  int c  = kp >> 2;
  int t  = kp & 3;
  Ap[idx] = f2bf(wproj[o * 1024 + t * 256 + c]);
}

// ---------------------------------------------------------------------------
// Prep W: wt[cv][k][c] fp32 (c-contiguous for lane=c conv reads)
// ---------------------------------------------------------------------------
__global__ void wprep_kernel(const float* __restrict__ wh1,
                             const float* __restrict__ wh2,
                             const float* __restrict__ wv1,
                             const float* __restrict__ wv2,
                             float* __restrict__ wt) {
  int idx = blockIdx.x * 256 + threadIdx.x;    // 0..9215
  int c = idx & 255;
  int q = idx >> 8;          // 0..35, block-uniform
  int cv = q / 9, k = q % 9;
  const float* src = (cv == 0) ? wh1 : (cv == 1) ? wh2 : (cv == 2) ? wv1 : wv2;
  wt[idx] = src[c * KS + k];
}

// ---------------------------------------------------------------------------
// Transpose: x[b][c][h][w] fp32 -> x_t[b][hw][c] bf16. 64x64 LDS tile.
// ---------------------------------------------------------------------------
__global__ __launch_bounds__(256)
void transpose_kernel(const float* __restrict__ x,
                      unsigned short* __restrict__ xt) {
  __shared__ float lds[64][65];
  int g   = blockIdx.x;             // 8192 = 8b x 4ct x 256hwt
  int b   = g >> 10;
  int r   = g & 1023;
  int ct  = r >> 8;
  int hwt = r & 255;
  int c0  = ct * 64, hw0 = hwt * 64;
  const float* in = x + (size_t)b * CC * (HH * WW);
  unsigned short* outp = xt + (size_t)b * (HH * WW) * CC;

  int tr  = threadIdx.x >> 4;        // 0..15
  int tc4 = (threadIdx.x & 15) * 4;  // 0,4..60

#pragma unroll
  for (int s = 0; s < 4; ++s) {
    int row = tr + s * 16;           // c-local
    float4 v = *(const float4*)(in + (size_t)(c0 + row) * (HH * WW) + hw0 + tc4);
    lds[row][tc4 + 0] = v.x; lds[row][tc4 + 1] = v.y;
    lds[row][tc4 + 2] = v.z; lds[row][tc4 + 3] = v.w;
  }
  __syncthreads();
#pragma unroll
  for (int s = 0; s < 4; ++s) {
    int row_o = tr + s * 16;         // hw-local
    ushort4 o;
    o.x = f2bf(lds[tc4 + 0][row_o]);
    o.y = f2bf(lds[tc4 + 1][row_o]);
    o.z = f2bf(lds[tc4 + 2][row_o]);
    o.w = f2bf(lds[tc4 + 3][row_o]);
    *(ushort4*)(outp + (size_t)(hw0 + row_o) * CC + c0 + tc4) = o;
  }
}

// ---------------------------------------------------------------------------
// Conv v6: identical to v5 EXCEPT __launch_bounds__(256, 4).
// r6 showed VGPR_Count=36 < the 54+ live floats (W 36 + hwin 9 + vv 9):
// compiler demoted weights to per-step global re-loads (~4.6x VMEM).
// Cap occupancy target at 4 waves/EU -> 128 VGPR -> W register-resident.
// ---------------------------------------------------------------------------
__global__ __launch_bounds__(256, 4)
void conv_kernel(const unsigned short* __restrict__ xt,
                 const float* __restrict__ wt,
                 unsigned short* __restrict__ Y) {
  int g    = blockIdx.x;           // 4096 = 8b x 128h x 4ws
  int b    = g & 7;                // consecutive g -> different XCD ~= b
  int rest = g >> 3;               // 0..511
  int h    = rest >> 2;
  int ws   = rest & 3;
  int c    = threadIdx.x;

  float W1[KS], W2[KS], W3[KS], W4[KS];
#pragma unroll
  for (int k = 0; k < KS; ++k) {
    W1[k] = wt[(0 * KS + k) * CC + c];
    W2[k] = wt[(1 * KS + k) * CC + c];
    W3[k] = wt[(2 * KS + k) * CC + c];
    W4[k] = wt[(3 * KS + k) * CC + c];
  }

  const unsigned short* xb = xt + (size_t)b * (HH * WW) * CC;
  int w0 = ws * 32;

  // horizontal ring: hwin[i] = x(h, w-4+i), i=0..8, for current w
  float hwin[9];
#pragma unroll
  for (int i = 0; i < 9; ++i) {
    int wp = w0 - 4 + i;
    hwin[i] = (wp >= 0 && wp < WW) ? bf2f(xb[((size_t)h * WW + wp) * CC + c]) : 0.f;
  }

  unsigned short* ybase = Y + ((size_t)((b * HH + h) * WW)) * KDIM + c * 4;

#pragma unroll 4
  for (int s = 0; s < 32; ++s) {
    int w = w0 + s;
    // vertical taps (center shared with hwin[4])
    float vv[9];
#pragma unroll
    for (int k = 0; k < 9; ++k) {
      if (k == 4) { vv[k] = hwin[4]; continue; }
      int r = h - 4 + k;                      // block-uniform predicate
      vv[k] = (r >= 0 && r < HH) ? bf2f(xb[((size_t)r * WW + w) * CC + c]) : 0.f;
    }

    float s1 = 0.f, s2 = 0.f, s3 = 0.f, s4 = 0.f;
#pragma unroll
    for (int k = 0; k < KS; ++k) {
      s1 = fmaf(hwin[k], W1[k], s1);
      s2 = fmaf(hwin[k], W2[k], s2);
      s3 = fmaf(vv[k],   W3[k], s3);
      s4 = fmaf(vv[k],   W4[k], s4);
    }
    unsigned u0 = (unsigned)f2bf(s1) | ((unsigned)f2bf(s2) << 16);
    unsigned u1 = (unsigned)f2bf(s3) | ((unsigned)f2bf(s4) << 16);
    *(uint2*)(ybase + (size_t)w * KDIM) = make_uint2(u0, u1);

    // slide horizontal window
#pragma unroll
    for (int i = 0; i < 8; ++i) hwin[i] = hwin[i + 1];
    int wn = w + 5;
    hwin[8] = (wn < WW) ? bf2f(xb[((size_t)h * WW + wn) * CC + c]) : 0.f;
  }
}

// ---------------------------------------------------------------------------
// GEMM v5: identical to v4 EXCEPT __launch_bounds__(512, 4) (VGPR cap 128,
// 2 blocks/CU). acc 64 + frags 32 + addressing ~fits; watch for spill.
// ---------------------------------------------------------------------------
__global__ __launch_bounds__(512, 4)
void gemm_kernel(const unsigned short* __restrict__ Ap,
                 const unsigned short* __restrict__ Yg,
                 float* __restrict__ out) {
  __shared__ short As[256 * 64];   // 32 KB (reused as f32 staging in epilogue)
  __shared__ short Bs[128 * 64];   // 16 KB

  int bid = blockIdx.x;
  int pt  = (bid & 7) * 128 + (bid >> 3);   // 1024 = 8 XCD x 128
  int tid  = threadIdx.x;
  int lane = tid & 63;
  int wv   = tid >> 6;
  int om   = wv & 3;                 // 0..3 : o base om*64
  int pn   = wv >> 2;                // 0..1 : p base pn*64
  int l15  = lane & 15;
  int kseg = lane >> 4;

  const short* A  = (const short*)Ap;
  const short* Bg = (const short*)Yg + (size_t)pt * 128 * KDIM;

  int srow = tid >> 3;               // 0..63
  int skc  = (tid & 7) * 8;

  f32x4 acc[4][4] = {};

  for (int k0 = 0; k0 < KDIM; k0 += 64) {
#pragma unroll
    for (int i = 0; i < 4; ++i) {
      int rr = i * 64 + srow;
      gload_lds16(A + (size_t)rr * KDIM + k0 + skc, &As[rr * 64 + skc]);
    }
#pragma unroll
    for (int i = 0; i < 2; ++i) {
      int rr = i * 64 + srow;
      gload_lds16(Bg + (size_t)rr * KDIM + k0 + skc, &Bs[rr * 64 + skc]);
    }
    __syncthreads();
#pragma unroll
    for (int kk = 0; kk < 2; ++kk) {
      bf16x8 af[4], bfr[4];
#pragma unroll
      for (int m = 0; m < 4; ++m)
        af[m] = *(const bf16x8*)&As[(om * 64 + m * 16 + l15) * 64 + kk * 32 + kseg * 8];
#pragma unroll
      for (int n = 0; n < 4; ++n)
        bfr[n] = *(const bf16x8*)&Bs[(pn * 64 + n * 16 + l15) * 64 + kk * 32 + kseg * 8];
#pragma unroll
      for (int m = 0; m < 4; ++m)
#pragma unroll
        for (int n = 0; n < 4; ++n)
          acc[m][n] = __builtin_amdgcn_mfma_f32_16x16x32_bf16(af[m], bfr[n],
                                                              acc[m][n], 0, 0, 0);
    }
    __syncthreads();
  }

  // Epilogue: restage through LDS, 32 o-rows per chunk, coalesced 512B rows.
  float* Ls = (float*)As;            // 32*132*4 = 16.9 KB <= 32 KB
  const int LP = 132;                // +4 pad: kseg rows land 16 banks apart
  int b2 = pt >> 7, h2 = pt & 127;
  int er = tid >> 4;                 // 0..31  (o-row within chunk)
  int ec = (tid & 15) * 8;           // 0..120 (w position)
  size_t obase = ((size_t)(b2 * 256) << 14) + (h2 << 7);

#pragma unroll
  for (int oc = 0; oc < 8; ++oc) {
    __syncthreads();
    if (om == (oc >> 1)) {
      int mb = (oc & 1) * 2;
#pragma unroll
      for (int mm = 0; mm < 2; ++mm) {
#pragma unroll
        for (int n = 0; n < 4; ++n) {
#pragma unroll
          for (int r = 0; r < 4; ++r) {
            int row = mm * 16 + kseg * 4 + r;          // 0..31
            int col = pn * 64 + n * 16 + l15;          // 0..127
            Ls[row * LP + col] = acc[mb + mm][n][r];
          }
        }
      }
    }
    __syncthreads();
    float4 v0 = *(const float4*)&Ls[er * LP + ec];
    float4 v1 = *(const float4*)&Ls[er * LP + ec + 4];
    size_t oaddr = obase + ((size_t)(oc * 32 + er) << 14) + ec;
    *(float4*)&out[oaddr] = make_float4(fmaxf(v0.x, 0.f), fmaxf(v0.y, 0.f),
                                        fmaxf(v0.z, 0.f), fmaxf(v0.w, 0.f));
    *(float4*)&out[oaddr + 4] = make_float4(fmaxf(v1.x, 0.f), fmaxf(v1.y, 0.f),
                                            fmaxf(v1.z, 0.f), fmaxf(v1.w, 0.f));
  }
}

extern "C" void kernel_launch(void* const* d_in, const int* in_sizes, int n_in,
                              void* d_out, int out_size, void* d_ws, size_t ws_size,
                              hipStream_t stream) {
  (void)in_sizes; (void)n_in; (void)out_size; (void)ws_size;
  const float* x     = (const float*)d_in[0];
  const float* wh1   = (const float*)d_in[1];
  const float* wh2   = (const float*)d_in[2];
  const float* wv1   = (const float*)d_in[3];
  const float* wv2   = (const float*)d_in[4];
  const float* wproj = (const float*)d_in[5];
  float* out = (float*)d_out;

  // ws layout: Y (268.4 MB) | x_t bf16 (67.1 MB) | Ap (512 KB) | wt (36 KB)
  char* wsb = (char*)d_ws;
  unsigned short* Yg = (unsigned short*)wsb;
  unsigned short* Xt = (unsigned short*)(wsb + (size_t)NPIX * KDIM * 2);
  unsigned short* Ap = (unsigned short*)(wsb + (size_t)NPIX * KDIM * 2
                                             + (size_t)NPIX * CC * 2);
  float* Wt = (float*)(wsb + (size_t)NPIX * KDIM * 2
                           + (size_t)NPIX * CC * 2 + (size_t)CC * KDIM * 2);

  hipLaunchKernelGGL(prep_kernel, dim3(1024), dim3(256), 0, stream, wproj, Ap);
  hipLaunchKernelGGL(wprep_kernel, dim3(36), dim3(256), 0, stream,
                     wh1, wh2, wv1, wv2, Wt);
  hipLaunchKernelGGL(transpose_kernel, dim3(8192), dim3(256), 0, stream, x, Xt);
  hipLaunchKernelGGL(conv_kernel, dim3(4096), dim3(256), 0, stream, Xt, Wt, Yg);
  hipLaunchKernelGGL(gemm_kernel, dim3(1024), dim3(512), 0, stream, Ap, Yg, out);
}

// Round 9
// 541.907 us; speedup vs baseline: 1.0927x; 1.0927x over previous
//
#include <hip/hip_runtime.h>
#include <hip/hip_bf16.h>

#define BB 8
#define CC 256
#define HH 128
#define WW 128
#define KS 9
#define NPIX (BB*HH*WW)   // 131072
#define KDIM (4*CC)       // 1024

// padded transposed-x layout: xt2[b][cg][hp=136][wp=136][cl=16] bf16
#define XROW   2176            // shorts per hp row = 136*16
#define XT2_CG 295936          // shorts per cg slab = 2176*136
#define XT2_B  4734976         // shorts per image  = 16*295936
#define XT2_BYTES 75759616u    // 8 * XT2_B * 2

typedef __attribute__((ext_vector_type(8))) short bf16x8;
typedef __attribute__((ext_vector_type(4))) float f32x4;

static __device__ __forceinline__ unsigned short f2bf(float f) {
  union { float f; unsigned u; } v; v.f = f;
  unsigned r = v.u + 0x7FFF + ((v.u >> 16) & 1);   // RNE
  return (unsigned short)(r >> 16);
}
static __device__ __forceinline__ float bf2f(unsigned short u) {
  union { unsigned u; float f; } v; v.u = ((unsigned)u) << 16;
  return v.f;
}

static __device__ __forceinline__ void gload_lds16(const void* g, void* l) {
  __builtin_amdgcn_global_load_lds(
      (const __attribute__((address_space(1))) void*)g,
      (__attribute__((address_space(3))) void*)l, 16, 0, 0);
}

// ---------------------------------------------------------------------------
// zero xt2 (borders must be 0; memset whole buffer, 75.7 MB)
// ---------------------------------------------------------------------------
__global__ void zero_kernel(uint4* __restrict__ p, long n16) {
  long i = (long)blockIdx.x * blockDim.x + threadIdx.x;
  long stride = (long)gridDim.x * blockDim.x;
  uint4 z = make_uint4(0, 0, 0, 0);
  for (; i < n16; i += stride) p[i] = z;
}

// ---------------------------------------------------------------------------
// Prep A': A'[o][k'] bf16, k' = c*4 + t, from wproj[o][t*256 + c] (fp32)
// ---------------------------------------------------------------------------
__global__ void prep_kernel(const float* __restrict__ wproj,
                            unsigned short* __restrict__ Ap) {
  int idx = blockIdx.x * 256 + threadIdx.x;    // 0 .. 262143
  int o  = idx >> 10;
  int kp = idx & 1023;
  int c  = kp >> 2;
  int t  = kp & 3;
  Ap[idx] = f2bf(wproj[o * 1024 + t * 256 + c]);
}

// ---------------------------------------------------------------------------
// Prep W: wt[cv][k][c] fp32 (c-contiguous)
// ---------------------------------------------------------------------------
__global__ void wprep_kernel(const float* __restrict__ wh1,
                             const float* __restrict__ wh2,
                             const float* __restrict__ wv1,
                             const float* __restrict__ wv2,
                             float* __restrict__ wt) {
  int idx = blockIdx.x * 256 + threadIdx.x;    // 0..9215
  int c = idx & 255;
  int q = idx >> 8;          // 0..35, block-uniform
  int cv = q / 9, k = q % 9;
  const float* src = (cv == 0) ? wh1 : (cv == 1) ? wh2 : (cv == 2) ? wv1 : wv2;
  wt[idx] = src[c * KS + k];
}

// ---------------------------------------------------------------------------
// Transpose v2: x[b][c][h][w] fp32 -> xt2[b][c>>4][h+4][w+4][c&15] bf16.
// Block = (b, ctile64, h, wtile64). Interior only; borders pre-zeroed.
// ---------------------------------------------------------------------------
__global__ __launch_bounds__(256)
void transpose_kernel(const float* __restrict__ x,
                      unsigned short* __restrict__ xt2) {
  __shared__ float lds[64][65];
  int g   = blockIdx.x;             // 8192 = b(8) ct(4) h(128) wt(2)
  int wt_ = g & 1;
  int h   = (g >> 1) & 127;
  int ct  = (g >> 8) & 3;
  int b   = g >> 10;
  int w0  = wt_ * 64;
  int tid = threadIdx.x;

  const float* xin = x + ((size_t)(b * 256 + ct * 64) << 14) + h * 128 + w0;
  int ci = tid >> 4;                 // 0..15 (+16*i)
  int w4 = (tid & 15) * 4;
#pragma unroll
  for (int i = 0; i < 4; ++i) {
    int c_ = ci + i * 16;
    float4 v = *(const float4*)(xin + ((size_t)c_ << 14) + w4);
    lds[c_][w4 + 0] = v.x; lds[c_][w4 + 1] = v.y;
    lds[c_][w4 + 2] = v.z; lds[c_][w4 + 3] = v.w;
  }
  __syncthreads();

  int wl  = (tid >> 6) * 16 + ((tid & 63) >> 2);   // 0..63
  int cl4 = (tid & 3) * 4;
#pragma unroll
  for (int g2 = 0; g2 < 4; ++g2) {
    ushort4 o;
    o.x = f2bf(lds[g2 * 16 + cl4 + 0][wl]);
    o.y = f2bf(lds[g2 * 16 + cl4 + 1][wl]);
    o.z = f2bf(lds[g2 * 16 + cl4 + 2][wl]);
    o.w = f2bf(lds[g2 * 16 + cl4 + 3][wl]);
    size_t dst = (size_t)b * XT2_B + (size_t)(ct * 4 + g2) * XT2_CG
               + (size_t)(h + 4) * XROW + (size_t)(w0 + wl + 4) * 16 + cl4;
    *(ushort4*)(xt2 + dst) = o;
  }
}

// ---------------------------------------------------------------------------
// Fused conv+GEMM: block = (b,h) pixel row. K-loop over cg (16 channels=64 k').
// Phase 1: stage contiguous 39KB x-slab (9 padded rows) via global_load_lds.
// Phase 2: compute B-tile [128 w][64 k'] (4 convs, no boundary branches),
//          ds_write XOR-swizzled (G4: fixes 16-way conflict of 128B-stride).
// Phase 3: A-frags register-direct from L2-hot Ap; 32 MFMA into acc.
// Y never materialized (saves 536 MB of HBM round-trip).
// ---------------------------------------------------------------------------
__global__ __launch_bounds__(512, 4)
void fused_kernel(const unsigned short* __restrict__ Ap,
                  const unsigned short* __restrict__ xt2,
                  const float* __restrict__ wt,
                  float* __restrict__ out) {
  __shared__ __align__(16) short Xs[9 * XROW];   // 39168 B
  __shared__ __align__(16) short Bs[128 * 64];   // 16384 B

  int bid = blockIdx.x;
  int pt  = (bid & 7) * 128 + (bid >> 3);   // image -> XCD, h-contiguous within
  int b   = pt >> 7, h = pt & 127;
  int tid = threadIdx.x;
  int lane = tid & 63;
  int wv  = tid >> 6;
  int om  = wv & 3, pn = wv >> 2;
  int l15 = lane & 15, kseg = lane >> 4;

  int cl = tid & 15;          // channel-in-group
  int wq = tid >> 4;          // 0..31 -> pixels wq*4..wq*4+3

  const short* A  = (const short*)Ap;
  const short* xb = (const short*)xt2 + (size_t)b * XT2_B + (size_t)h * XROW;

  f32x4 acc[4][4] = {};

  for (int cg = 0; cg < 16; ++cg) {
    // ---- phase 1: stage x-slab (contiguous 39168 B) ----
    const char* src = (const char*)(xb + (size_t)cg * XT2_CG);
#pragma unroll
    for (int i = 0; i < 5; ++i) {
      int off = i * 8192 + tid * 16;
      if (off < 9 * XROW * 2)
        gload_lds16(src + off, (char*)Xs + off);
    }
    __syncthreads();

    // A-frags for this cg: issue early, consumed after next barrier
    bf16x8 af[2][4];
#pragma unroll
    for (int kk = 0; kk < 2; ++kk) {
      int kg = cg * 64 + kk * 32 + kseg * 8;
#pragma unroll
      for (int m = 0; m < 4; ++m)
        af[kk][m] = *(const bf16x8*)(A + (size_t)(om * 64 + m * 16 + l15) * KDIM + kg);
    }

    // ---- phase 2: B-tile compute ----
    int c = cg * 16 + cl;
    float s[4][4];
#pragma unroll
    for (int dw = 0; dw < 4; ++dw)
#pragma unroll
      for (int t = 0; t < 4; ++t) s[dw][t] = 0.f;
#pragma unroll
    for (int j = 0; j < KS; ++j) {
      float w1 = wt[(0 * KS + j) * CC + c];
      float w2 = wt[(1 * KS + j) * CC + c];
      float w3 = wt[(2 * KS + j) * CC + c];
      float w4 = wt[(3 * KS + j) * CC + c];
#pragma unroll
      for (int dw = 0; dw < 4; ++dw) {
        int w = wq * 4 + dw;
        float xh = bf2f((unsigned short)Xs[4 * XROW + (w + j) * 16 + cl]);
        float xv = bf2f((unsigned short)Xs[j * XROW + (w + 4) * 16 + cl]);
        s[dw][0] = fmaf(xh, w1, s[dw][0]);
        s[dw][1] = fmaf(xh, w2, s[dw][1]);
        s[dw][2] = fmaf(xv, w3, s[dw][2]);
        s[dw][3] = fmaf(xv, w4, s[dw][3]);
      }
    }
#pragma unroll
    for (int dw = 0; dw < 4; ++dw) {
      int w = wq * 4 + dw;
      unsigned u0 = (unsigned)f2bf(s[dw][0]) | ((unsigned)f2bf(s[dw][1]) << 16);
      unsigned u1 = (unsigned)f2bf(s[dw][2]) | ((unsigned)f2bf(s[dw][3]) << 16);
      int byt = (w * 128 + cl * 8) ^ ((w & 7) << 4);   // st-swizzle
      *(uint2*)((char*)Bs + byt) = make_uint2(u0, u1);
    }
    __syncthreads();

    // ---- phase 3: MFMA ----
#pragma unroll
    for (int kk = 0; kk < 2; ++kk) {
      bf16x8 bfr[4];
#pragma unroll
      for (int n = 0; n < 4; ++n) {
        int row = pn * 64 + n * 16 + l15;
        int byt = (row * 128 + kk * 64 + kseg * 16) ^ ((row & 7) << 4);
        bfr[n] = *(const bf16x8*)((const char*)Bs + byt);
      }
#pragma unroll
      for (int m = 0; m < 4; ++m)
#pragma unroll
        for (int n = 0; n < 4; ++n)
          acc[m][n] = __builtin_amdgcn_mfma_f32_16x16x32_bf16(af[kk][m], bfr[n],
                                                              acc[m][n], 0, 0, 0);
    }
    __syncthreads();
  }

  // ---- epilogue: LDS-restaged coalesced stores (512B rows) ----
  float* Ls = (float*)Xs;            // 32*132*4 = 16.9 KB <= 39 KB
  const int LP = 132;
  int b2 = pt >> 7, h2 = pt & 127;
  int er = tid >> 4;                 // 0..31
  int ec = (tid & 15) * 8;           // 0..120
  size_t obase = ((size_t)(b2 * 256) << 14) + (h2 << 7);

#pragma unroll
  for (int oc = 0; oc < 8; ++oc) {
    __syncthreads();
    if (om == (oc >> 1)) {
      int mb = (oc & 1) * 2;
#pragma unroll
      for (int mm = 0; mm < 2; ++mm) {
#pragma unroll
        for (int n = 0; n < 4; ++n) {
#pragma unroll
          for (int r = 0; r < 4; ++r) {
            int row = mm * 16 + kseg * 4 + r;          // 0..31
            int col = pn * 64 + n * 16 + l15;          // 0..127
            Ls[row * LP + col] = acc[mb + mm][n][r];
          }
        }
      }
    }
    __syncthreads();
    float4 v0 = *(const float4*)&Ls[er * LP + ec];
    float4 v1 = *(const float4*)&Ls[er * LP + ec + 4];
    size_t oaddr = obase + ((size_t)(oc * 32 + er) << 14) + ec;
    *(float4*)&out[oaddr] = make_float4(fmaxf(v0.x, 0.f), fmaxf(v0.y, 0.f),
                                        fmaxf(v0.z, 0.f), fmaxf(v0.w, 0.f));
    *(float4*)&out[oaddr + 4] = make_float4(fmaxf(v1.x, 0.f), fmaxf(v1.y, 0.f),
                                            fmaxf(v1.z, 0.f), fmaxf(v1.w, 0.f));
  }
}

extern "C" void kernel_launch(void* const* d_in, const int* in_sizes, int n_in,
                              void* d_out, int out_size, void* d_ws, size_t ws_size,
                              hipStream_t stream) {
  (void)in_sizes; (void)n_in; (void)out_size; (void)ws_size;
  const float* x     = (const float*)d_in[0];
  const float* wh1   = (const float*)d_in[1];
  const float* wh2   = (const float*)d_in[2];
  const float* wv1   = (const float*)d_in[3];
  const float* wv2   = (const float*)d_in[4];
  const float* wproj = (const float*)d_in[5];
  float* out = (float*)d_out;

  // ws layout: xt2 (75.76 MB) | Ap (512 KB) | wt (36 KB)
  char* wsb = (char*)d_ws;
  unsigned short* Xt2 = (unsigned short*)wsb;
  unsigned short* Ap  = (unsigned short*)(wsb + XT2_BYTES);
  float* Wt           = (float*)(wsb + XT2_BYTES + (size_t)CC * KDIM * 2);

  hipLaunchKernelGGL(zero_kernel, dim3(2048), dim3(256), 0, stream,
                     (uint4*)Xt2, (long)(XT2_BYTES / 16));
  hipLaunchKernelGGL(prep_kernel, dim3(1024), dim3(256), 0, stream, wproj, Ap);
  hipLaunchKernelGGL(wprep_kernel, dim3(36), dim3(256), 0, stream,
                     wh1, wh2, wv1, wv2, Wt);
  hipLaunchKernelGGL(transpose_kernel, dim3(8192), dim3(256), 0, stream, x, Xt2);
  hipLaunchKernelGGL(fused_kernel, dim3(1024), dim3(512), 0, stream,
                     Ap, Xt2, Wt, out);
}